// Round 16
// baseline (126.515 us; speedup 1.0000x reference)
//
#include <hip/hip_runtime.h>

#define HIDDEN 1024
#define NB 8
#define SEQ 2048
#define DH 64

typedef long long i64;
typedef unsigned short u16;
typedef __attribute__((ext_vector_type(8))) _Float16 half8;  // 4 VGPRs = 8 fp16
typedef __attribute__((ext_vector_type(4))) float f32x4;

#define MFMA16F __builtin_amdgcn_mfma_f32_16x16x32_f16

__device__ __forceinline__ u16 f2h(float x) {
    _Float16 h = (_Float16)x;                 // RNE
    return __builtin_bit_cast(u16, h);
}
__device__ __forceinline__ void gl_lds16(const void* g, void* l) {
    __builtin_amdgcn_global_load_lds(
        (const __attribute__((address_space(1))) unsigned int*)g,
        (__attribute__((address_space(3))) unsigned int*)l, 16, 0, 0);
}

// ---------------------------------------------------------------------------
// Prepass: W[1024][64] (x3) -> Wimg[te][p][n][pos] fp16, p = 16 phases of
// BK=64, n = out col, pos = 16B block (8 per row); position pos holds global
// k-chunk (pos ^ (n&7)). (byte-identical to round-15 passing version)
// ---------------------------------------------------------------------------
__global__ __launch_bounds__(256) void wimg_prep16(
    const float* __restrict__ Wq, const float* __restrict__ Wk, const float* __restrict__ Wv,
    u16* __restrict__ Wimg)
{
    const int t = blockIdx.x * 256 + threadIdx.x;   // 24576 threads
    const int te = t >> 13;
    const int rem = t & 8191;
    const int p = rem >> 9;                          // 0..15
    const int rem2 = rem & 511;
    const int n = rem2 >> 3;                         // 0..63
    const int pos = rem2 & 7;                        // 16B block in row
    const float* W = te == 0 ? Wq : te == 1 ? Wk : Wv;
    const int g = pos ^ (n & 7);
    const int k0 = p * 64 + g * 8;
    u16* dst = Wimg + (i64)t * 8;
    #pragma unroll
    for (int j = 0; j < 8; ++j)
        dst[j] = f2h(W[(i64)(k0 + j) * DH + n]);
}

// ---------------------------------------------------------------------------
// Projection v11 = v10 + DEEP A-PIPELINE (ring-5, depth 4) with exact
// counted vmcnt per step (in-order retirement, m135 semantics).
// 3072 single-wave blocks, 16 rows x 64 cols, K in 16 steps (BK=64).
// Issue order: prologue A0..A3,W0; step s: W(s+1), A(s+4).
// Wait at step s = youngest needed op:
//   s=0: W0 -> younger A4+W1 = vmcnt(12)
//   1<=s<=11: W(s) -> younger A(s+3)+W(s+1)+A(s+4) = vmcnt(16)
//   s=12: vmcnt(12); s=13: vmcnt(8); s=14: vmcnt(8); s=15: vmcnt(0)
// A(s) is thus issued 4 compute phases before its wait (covers ~900cy L3);
// W(s) 1 phase (L2-fast, attn-proven). No __syncthreads. LDS 36KB -> 4/CU.
// Compute body byte-identical to v10 (absmax 4.88e-4 proven).
// ---------------------------------------------------------------------------
__global__ __launch_bounds__(64) void proj_mfma11(
    const float* __restrict__ qh, const float* __restrict__ kh, const float* __restrict__ vh,
    const u16* __restrict__ Wimg,
    const float* __restrict__ bq, const float* __restrict__ bk, const float* __restrict__ bv,
    u16* __restrict__ Qb, u16* __restrict__ Kb, u16* __restrict__ Vt)
{
    const int te = blockIdx.y;
    const float* A    = te == 0 ? qh : te == 1 ? kh : vh;
    const float* bias = te == 0 ? bq : te == 1 ? bk : bv;
    const int row0 = blockIdx.x << 4;          // 1024 tiles of 16 rows
    const int lane = threadIdx.x;
    const int lr = lane & 15, lg = lane >> 4;

    __shared__ __attribute__((aligned(16))) float AL[5][1024];   // 20KB ring
    __shared__ __attribute__((aligned(16))) u16  WL[2][4096];    // 16KB ring

    const u16* Wte = Wimg + (i64)te * 16 * 4096;

    // A staging sources: gl_lds i covers rows 4i..4i+3 (256B each, linear dst);
    // lane's dst block = lane&15; SOURCE block = (lane&15) ^ (row&15)  [rule 21]
    const float* asrc[4];
    #pragma unroll
    for (int i = 0; i < 4; ++i) {
        const int ar = 4 * i + (lane >> 4);                  // this lane's row
        const int ab = (lane & 15) ^ (ar & 15);              // source 16B block
        asrc[i] = A + (i64)(row0 + ar) * HIDDEN + (ab << 2);
    }
    const u16* wsrc = Wte + (lane << 3);                     // linear image

    f32x4 acc[4] = {};

#define STAGE_A(S, B) { \
        _Pragma("unroll") \
        for (int i_ = 0; i_ < 4; ++i_) \
            gl_lds16(asrc[i_] + (S) * 64, &AL[B][i_ * 256]); }
#define STAGE_W(S, B) { \
        _Pragma("unroll") \
        for (int j_ = 0; j_ < 8; ++j_) \
            gl_lds16(wsrc + (S) * 4096 + j_ * 512, &WL[B][j_ * 512]); }

#define COMPUTE(AB, WB) { \
        _Pragma("unroll") \
        for (int ks = 0; ks < 2; ++ks) { \
            const int b0 = ks * 8 + lg * 2; \
            const float4 fa = *(const float4*)&AL[AB][lr * 64 + ((b0 ^ lr) << 2)]; \
            const float4 fb = *(const float4*)&AL[AB][lr * 64 + (((b0 + 1) ^ lr) << 2)]; \
            half8 a; \
            a[0] = (_Float16)fa.x; a[1] = (_Float16)fa.y; \
            a[2] = (_Float16)fa.z; a[3] = (_Float16)fa.w; \
            a[4] = (_Float16)fb.x; a[5] = (_Float16)fb.y; \
            a[6] = (_Float16)fb.z; a[7] = (_Float16)fb.w; \
            _Pragma("unroll") \
            for (int nt = 0; nt < 4; ++nt) { \
                const int n = nt * 16 + lr; \
                const int pos = (ks * 4 + lg) ^ (n & 7); \
                const half8 b = *(const half8*)&WL[WB][n * 64 + (pos << 3)]; \
                acc[nt] = MFMA16F(a, b, acc[nt], 0, 0, 0); \
            } \
        } }

    // prologue: A depth 4, W depth 1
    STAGE_A(0, 0) STAGE_A(1, 1) STAGE_A(2, 2) STAGE_A(3, 3)
    STAGE_W(0, 0)

    // step 0 (peeled: W0 is youngest needed; A4+W1 younger = 12)
    STAGE_W(1, 1)
    STAGE_A(4, 4)
    asm volatile("s_waitcnt vmcnt(12)" ::: "memory");
    COMPUTE(0, 0)

    // steps 1..11: steady state
    int ab_use = 1, ab_stage = 0;
    #pragma unroll 1
    for (int s = 1; s < 12; ++s) {
        STAGE_W(s + 1, (s + 1) & 1)
        STAGE_A(s + 4, ab_stage)
        asm volatile("s_waitcnt vmcnt(16)" ::: "memory");
        COMPUTE(ab_use, s & 1)
        if (++ab_use == 5) ab_use = 0;
        if (++ab_stage == 5) ab_stage = 0;
    }

    // tail: s = 12..15 (A exhausted; exact counts)
    STAGE_W(13, 1)
    asm volatile("s_waitcnt vmcnt(12)" ::: "memory");
    COMPUTE(2, 0)
    STAGE_W(14, 0)
    asm volatile("s_waitcnt vmcnt(8)" ::: "memory");
    COMPUTE(3, 1)
    STAGE_W(15, 1)
    asm volatile("s_waitcnt vmcnt(8)" ::: "memory");
    COMPUTE(4, 0)
    asm volatile("s_waitcnt vmcnt(0)" ::: "memory");
    COMPUTE(0, 1)

#undef STAGE_A
#undef STAGE_W
#undef COMPUTE

    // epilogue: D layout col=lane&15 (within nt), row=(lane>>4)*4+reg
    #pragma unroll
    for (int nt = 0; nt < 4; ++nt) {
        const int col = nt * 16 + lr;
        const float bb = bias[col];
        #pragma unroll
        for (int r = 0; r < 4; ++r) {
            const i64 grow = row0 + (lg << 2) + r;
            const u16 v = f2h(acc[nt][r] + bb);
            if (te == 0)      Qb[grow * DH + col] = v;
            else if (te == 1) Kb[grow * DH + col] = v;
            else {
                const i64 bb2 = grow >> 11, key = grow & 2047;
                Vt[(bb2 * DH + col) * SEQ + key] = v;
            }
        }
    }
}

// ---------------------------------------------------------------------------
// Attention: 1024 single-wave blocks (16 q-rows each), no barriers.
// (byte-identical to the round-15 passing fp16 version)
// ---------------------------------------------------------------------------
__global__ __launch_bounds__(64) void attn_mfma(
    const u16* __restrict__ Qb, const u16* __restrict__ Kb, const u16* __restrict__ Vt,
    const int* __restrict__ mask, float* __restrict__ out)
{
    __shared__ __attribute__((aligned(16))) u16 Kl[2][64 * 64];
    __shared__ __attribute__((aligned(16))) u16 Vl[2][64 * 64];
    __shared__ __attribute__((aligned(16))) u16 Pl[16][72];

    const int lane = threadIdx.x;
    const int lr = lane & 15, lg = lane >> 4;
    const int b  = blockIdx.x >> 7;
    const int q0 = (blockIdx.x & 127) << 4;

    const i64 qrow = (i64)b * SEQ + q0 + lr;
    const half8 qf0 = *(const half8*)(Qb + qrow * DH + lg * 8);
    const half8 qf1 = *(const half8*)(Qb + qrow * DH + 32 + lg * 8);

    const int srow = lane >> 3;   // 0..7 (+8i)
    const int scb  = lane & 7;    // 16B block

    f32x4 oacc[4] = {};
    float rs0 = 0.f, rs1 = 0.f, rs2 = 0.f, rs3 = 0.f;

    // prologue: stage tile 0 into buf 0 (16 loads)
    {
        const i64 kbase = (i64)b * SEQ;
        #pragma unroll
        for (int i = 0; i < 8; ++i) {
            int row = i * 8 + srow, cb = scb ^ (row & 7);
            gl_lds16(Kb + (kbase + row) * DH + cb * 8, &Kl[0][i * 512]);
        }
        #pragma unroll
        for (int i = 0; i < 8; ++i) {
            int row = i * 8 + srow, cb = scb ^ (row & 7);
            gl_lds16(Vt + ((i64)b * DH + row) * SEQ + cb * 8, &Vl[0][i * 512]);
        }
    }

    #pragma unroll 1
    for (int t = 0; t < 32; ++t) {
        const int kt = t * 64;
        const int buf = t & 1;

        int mv[16];
        #pragma unroll
        for (int tt = 0; tt < 4; ++tt)
            #pragma unroll
            for (int r = 0; r < 4; ++r)
                mv[tt * 4 + r] =
                    mask[((i64)b * SEQ + q0 + lg * 4 + r) * SEQ + kt + tt * 16 + lr];

        if (t < 31) {
            const int kn = kt + 64;
            const i64 kbase = (i64)b * SEQ + kn;
            #pragma unroll
            for (int i = 0; i < 8; ++i) {
                int row = i * 8 + srow, cb = scb ^ (row & 7);
                gl_lds16(Kb + (kbase + row) * DH + cb * 8, &Kl[buf ^ 1][i * 512]);
            }
            #pragma unroll
            for (int i = 0; i < 8; ++i) {
                int row = i * 8 + srow, cb = scb ^ (row & 7);
                gl_lds16(Vt + ((i64)b * DH + row) * SEQ + kn + cb * 8, &Vl[buf ^ 1][i * 512]);
            }
            asm volatile("s_waitcnt vmcnt(32)" ::: "memory");
        } else {
            asm volatile("s_waitcnt vmcnt(16)" ::: "memory");
        }

        f32x4 sacc[4] = {};
        #pragma unroll
        for (int tt = 0; tt < 4; ++tt) {
            int row = tt * 16 + lr, x = row & 7;
            half8 k0 = *(const half8*)&Kl[buf][row * 64 + ((lg) ^ x) * 8];
            half8 k1 = *(const half8*)&Kl[buf][row * 64 + ((lg + 4) ^ x) * 8];
            sacc[tt] = MFMA16F(qf0, k0, sacc[tt], 0, 0, 0);
            sacc[tt] = MFMA16F(qf1, k1, sacc[tt], 0, 0, 0);
        }

        #pragma unroll
        for (int tt = 0; tt < 4; ++tt) {
            #pragma unroll
            for (int r = 0; r < 4; ++r) {
                float p = (mv[tt * 4 + r] != 0) ? __expf(sacc[tt][r] * 0.125f) : 0.0f;
                if      (r == 0) rs0 += p;
                else if (r == 1) rs1 += p;
                else if (r == 2) rs2 += p;
                else             rs3 += p;
                Pl[lg * 4 + r][tt * 16 + lr] = f2h(p);
            }
        }

        const half8 p0 = *(const half8*)&Pl[lr][lg * 8];
        const half8 p1 = *(const half8*)&Pl[lr][32 + lg * 8];
        #pragma unroll
        for (int vt = 0; vt < 4; ++vt) {
            int row = vt * 16 + lr, x = row & 7;
            half8 v0 = *(const half8*)&Vl[buf][row * 64 + ((lg) ^ x) * 8];
            half8 v1 = *(const half8*)&Vl[buf][row * 64 + ((lg + 4) ^ x) * 8];
            oacc[vt] = MFMA16F(p0, v0, oacc[vt], 0, 0, 0);
            oacc[vt] = MFMA16F(p1, v1, oacc[vt], 0, 0, 0);
        }
    }

    float rs[4] = {rs0, rs1, rs2, rs3};
    #pragma unroll
    for (int r = 0; r < 4; ++r) {
        float v = rs[r];
        v += __shfl_xor(v, 1, 64);
        v += __shfl_xor(v, 2, 64);
        v += __shfl_xor(v, 4, 64);
        v += __shfl_xor(v, 8, 64);
        rs[r] = 1.0f / v;
    }
    #pragma unroll
    for (int vt = 0; vt < 4; ++vt)
        #pragma unroll
        for (int r = 0; r < 4; ++r)
            out[((i64)b * SEQ + q0 + lg * 4 + r) * DH + vt * 16 + lr] = oacc[vt][r] * rs[r];
}

extern "C" void kernel_launch(void* const* d_in, const int* in_sizes, int n_in,
                              void* d_out, int out_size, void* d_ws, size_t ws_size,
                              hipStream_t stream) {
    const float* kh   = (const float*)d_in[0];
    const float* qh   = (const float*)d_in[1];
    const float* vh   = (const float*)d_in[2];
    const int*   mask = (const int*)  d_in[3];
    const float* Wq   = (const float*)d_in[4];
    const float* bq   = (const float*)d_in[5];
    const float* Wk   = (const float*)d_in[6];
    const float* bk   = (const float*)d_in[7];
    const float* Wv   = (const float*)d_in[8];
    const float* bv   = (const float*)d_in[9];
    float* out = (float*)d_out;

    u16* Wimg = (u16*)d_ws;                      // 3*16*4096 u16 = 384 KB
    u16* Qb   = Wimg + 3 * 16 * 4096;            // 2 MB each
    u16* Kb   = Qb + (i64)NB * SEQ * DH;
    u16* Vt   = Kb + (i64)NB * SEQ * DH;         // [b][vd][key]

    wimg_prep16<<<96, 256, 0, stream>>>(Wq, Wk, Wv, Wimg);
    proj_mfma11<<<dim3(1024, 3), 64, 0, stream>>>(qh, kh, vh, Wimg,
                                                  bq, bk, bv, Qb, Kb, Vt);
    attn_mfma<<<1024, 64, 0, stream>>>(Qb, Kb, Vt, mask, out);
}

// Round 17
// 116.508 us; speedup vs baseline: 1.0859x; 1.0859x over previous
//
#include <hip/hip_runtime.h>

#define HIDDEN 1024
#define NB 8
#define SEQ 2048
#define DH 64

typedef long long i64;
typedef unsigned short u16;
typedef __attribute__((ext_vector_type(8))) _Float16 half8;  // 4 VGPRs = 8 fp16
typedef __attribute__((ext_vector_type(4))) float f32x4;

#define MFMA16F __builtin_amdgcn_mfma_f32_16x16x32_f16

__device__ __forceinline__ u16 f2h(float x) {
    _Float16 h = (_Float16)x;                 // RNE
    return __builtin_bit_cast(u16, h);
}
__device__ __forceinline__ void gl_lds16(const void* g, void* l) {
    __builtin_amdgcn_global_load_lds(
        (const __attribute__((address_space(1))) unsigned int*)g,
        (__attribute__((address_space(3))) unsigned int*)l, 16, 0, 0);
}

// ---------------------------------------------------------------------------
// Prepass: W[1024][64] (x3) -> Wimg[te][p][n][pos] fp16, p = 16 phases of
// BK=64, n = out col, pos = 16B block (8 per row); position pos holds global
// k-chunk (pos ^ (n&7)). (byte-identical to round-16 passing version)
// ---------------------------------------------------------------------------
__global__ __launch_bounds__(256) void wimg_prep16(
    const float* __restrict__ Wq, const float* __restrict__ Wk, const float* __restrict__ Wv,
    u16* __restrict__ Wimg)
{
    const int t = blockIdx.x * 256 + threadIdx.x;   // 24576 threads
    const int te = t >> 13;
    const int rem = t & 8191;
    const int p = rem >> 9;                          // 0..15
    const int rem2 = rem & 511;
    const int n = rem2 >> 3;                         // 0..63
    const int pos = rem2 & 7;                        // 16B block in row
    const float* W = te == 0 ? Wq : te == 1 ? Wk : Wv;
    const int g = pos ^ (n & 7);
    const int k0 = p * 64 + g * 8;
    u16* dst = Wimg + (i64)t * 8;
    #pragma unroll
    for (int j = 0; j < 8; ++j)
        dst[j] = f2h(W[(i64)(k0 + j) * DH + n]);
}

// ---------------------------------------------------------------------------
// Projection v12 = v8's skeleton (drain+barrier once per phase, proven best
// at 76us) x v10's staging/compute bodies (proven correct, 0 conflicts),
// at BK=64 so LDS = 32KB -> 5 blocks/CU (20 waves/CU, 2.5x v8's TLP).
// Block = 256 thr = 4 waves, tile 32 rows x 64 cols; wave w -> rows
// (w&1)*16.., cols (w>>1)*32.. K in 16 phases of 64.
// Per phase: vmcnt(0) -> barrier -> stage(p+1) [4 gl_lds/wave] -> compute(p)
// [2 ks x (2 ds_read_b128 A + cvt + 2 MFMA)]. Other blocks cover the drain.
// ---------------------------------------------------------------------------
__global__ __launch_bounds__(256) void proj_mfma12(
    const float* __restrict__ qh, const float* __restrict__ kh, const float* __restrict__ vh,
    const u16* __restrict__ Wimg,
    const float* __restrict__ bq, const float* __restrict__ bk, const float* __restrict__ bv,
    u16* __restrict__ Qb, u16* __restrict__ Kb, u16* __restrict__ Vt)
{
    const int te = blockIdx.y;
    const float* A    = te == 0 ? qh : te == 1 ? kh : vh;
    const float* bias = te == 0 ? bq : te == 1 ? bk : bv;
    const int row0 = blockIdx.x << 5;          // 512 tiles of 32 rows
    const int t = threadIdx.x;
    const int w = t >> 6, lane = t & 63;
    const int lr = lane & 15, lg = lane >> 4;
    const int wr = (w & 1) << 4;               // wave row offset
    const int wc = (w >> 1) << 5;              // wave col offset

    __shared__ __attribute__((aligned(16))) float AL[2][32 * 64];   // 8KB x2
    __shared__ __attribute__((aligned(16))) u16  WL[2][64 * 64];    // 8KB x2

    const u16* Wte = Wimg + (i64)te * 16 * 4096;

    // A staging: wave w covers slab rows 8w..8w+7; gl_lds i covers 4 rows
    // (256B each, linear dst). Lane dst block = lane&15 of row
    // ar = 8w+4i+(lane>>4); SOURCE block = (lane&15) ^ (ar&15)   [rule 21]
    const float* asrc[2]; int adst[2];
    #pragma unroll
    for (int i = 0; i < 2; ++i) {
        const int ar = 8 * w + 4 * i + (lane >> 4);          // slab row
        const int ab = (lane & 15) ^ (ar & 15);              // source 16B block
        asrc[i] = A + (i64)(row0 + ar) * HIDDEN + (ab << 2);
        adst[i] = (8 * w + 4 * i) * 64;
    }
    // W staging: wave w covers image rows 16w..16w+15; gl_lds j covers 8 rows
    const u16* wsrc[2]; int wdst[2];
    #pragma unroll
    for (int j = 0; j < 2; ++j) {
        const int n0 = 16 * w + 8 * j;
        wsrc[j] = Wte + n0 * 64 + (lane << 3);               // linear image
        wdst[j] = n0 * 64;
    }

    f32x4 acc[2] = {};

#define STAGE(P, B) { \
        _Pragma("unroll") \
        for (int i_ = 0; i_ < 2; ++i_) \
            gl_lds16(asrc[i_] + (P) * 64, &AL[B][adst[i_]]); \
        _Pragma("unroll") \
        for (int j_ = 0; j_ < 2; ++j_) \
            gl_lds16(wsrc[j_] + (P) * 4096, &WL[B][wdst[j_]]); }

#define COMPUTE(B) { \
        _Pragma("unroll") \
        for (int ks = 0; ks < 2; ++ks) { \
            const int b0 = ks * 8 + lg * 2; \
            const float4 fa = *(const float4*)&AL[B][(wr + lr) * 64 + ((b0 ^ lr) << 2)]; \
            const float4 fb = *(const float4*)&AL[B][(wr + lr) * 64 + (((b0 + 1) ^ lr) << 2)]; \
            half8 a; \
            a[0] = (_Float16)fa.x; a[1] = (_Float16)fa.y; \
            a[2] = (_Float16)fa.z; a[3] = (_Float16)fa.w; \
            a[4] = (_Float16)fb.x; a[5] = (_Float16)fb.y; \
            a[6] = (_Float16)fb.z; a[7] = (_Float16)fb.w; \
            _Pragma("unroll") \
            for (int nt = 0; nt < 2; ++nt) { \
                const int n = wc + nt * 16 + lr; \
                const int pos = (ks * 4 + lg) ^ (n & 7); \
                const half8 b = *(const half8*)&WL[B][n * 64 + (pos << 3)]; \
                acc[nt] = MFMA16F(a, b, acc[nt], 0, 0, 0); \
            } \
        } }

    STAGE(0, 0)

    int buf = 0;
    #pragma unroll 1
    for (int p = 0; p < 16; ++p) {
        asm volatile("s_waitcnt vmcnt(0)" ::: "memory");   // stage(p) done
        __syncthreads();                                    // visible; buf^1 free
        if (p < 15) STAGE(p + 1, buf ^ 1)
        COMPUTE(buf)
        buf ^= 1;
    }
#undef STAGE
#undef COMPUTE

    // epilogue: D layout col=lane&15 (within nt), row=(lane>>4)*4+reg
    #pragma unroll
    for (int nt = 0; nt < 2; ++nt) {
        const int col = wc + nt * 16 + lr;
        const float bb = bias[col];
        #pragma unroll
        for (int r = 0; r < 4; ++r) {
            const i64 grow = row0 + wr + (lg << 2) + r;
            const u16 v = f2h(acc[nt][r] + bb);
            if (te == 0)      Qb[grow * DH + col] = v;
            else if (te == 1) Kb[grow * DH + col] = v;
            else {
                const i64 bb2 = grow >> 11, key = grow & 2047;
                Vt[(bb2 * DH + col) * SEQ + key] = v;
            }
        }
    }
}

// ---------------------------------------------------------------------------
// Attention: 1024 single-wave blocks (16 q-rows each), no barriers.
// (byte-identical to the round-16 passing fp16 version)
// ---------------------------------------------------------------------------
__global__ __launch_bounds__(64) void attn_mfma(
    const u16* __restrict__ Qb, const u16* __restrict__ Kb, const u16* __restrict__ Vt,
    const int* __restrict__ mask, float* __restrict__ out)
{
    __shared__ __attribute__((aligned(16))) u16 Kl[2][64 * 64];
    __shared__ __attribute__((aligned(16))) u16 Vl[2][64 * 64];
    __shared__ __attribute__((aligned(16))) u16 Pl[16][72];

    const int lane = threadIdx.x;
    const int lr = lane & 15, lg = lane >> 4;
    const int b  = blockIdx.x >> 7;
    const int q0 = (blockIdx.x & 127) << 4;

    const i64 qrow = (i64)b * SEQ + q0 + lr;
    const half8 qf0 = *(const half8*)(Qb + qrow * DH + lg * 8);
    const half8 qf1 = *(const half8*)(Qb + qrow * DH + 32 + lg * 8);

    const int srow = lane >> 3;   // 0..7 (+8i)
    const int scb  = lane & 7;    // 16B block

    f32x4 oacc[4] = {};
    float rs0 = 0.f, rs1 = 0.f, rs2 = 0.f, rs3 = 0.f;

    // prologue: stage tile 0 into buf 0 (16 loads)
    {
        const i64 kbase = (i64)b * SEQ;
        #pragma unroll
        for (int i = 0; i < 8; ++i) {
            int row = i * 8 + srow, cb = scb ^ (row & 7);
            gl_lds16(Kb + (kbase + row) * DH + cb * 8, &Kl[0][i * 512]);
        }
        #pragma unroll
        for (int i = 0; i < 8; ++i) {
            int row = i * 8 + srow, cb = scb ^ (row & 7);
            gl_lds16(Vt + ((i64)b * DH + row) * SEQ + cb * 8, &Vl[0][i * 512]);
        }
    }

    #pragma unroll 1
    for (int t = 0; t < 32; ++t) {
        const int kt = t * 64;
        const int buf = t & 1;

        int mv[16];
        #pragma unroll
        for (int tt = 0; tt < 4; ++tt)
            #pragma unroll
            for (int r = 0; r < 4; ++r)
                mv[tt * 4 + r] =
                    mask[((i64)b * SEQ + q0 + lg * 4 + r) * SEQ + kt + tt * 16 + lr];

        if (t < 31) {
            const int kn = kt + 64;
            const i64 kbase = (i64)b * SEQ + kn;
            #pragma unroll
            for (int i = 0; i < 8; ++i) {
                int row = i * 8 + srow, cb = scb ^ (row & 7);
                gl_lds16(Kb + (kbase + row) * DH + cb * 8, &Kl[buf ^ 1][i * 512]);
            }
            #pragma unroll
            for (int i = 0; i < 8; ++i) {
                int row = i * 8 + srow, cb = scb ^ (row & 7);
                gl_lds16(Vt + ((i64)b * DH + row) * SEQ + kn + cb * 8, &Vl[buf ^ 1][i * 512]);
            }
            asm volatile("s_waitcnt vmcnt(32)" ::: "memory");
        } else {
            asm volatile("s_waitcnt vmcnt(16)" ::: "memory");
        }

        f32x4 sacc[4] = {};
        #pragma unroll
        for (int tt = 0; tt < 4; ++tt) {
            int row = tt * 16 + lr, x = row & 7;
            half8 k0 = *(const half8*)&Kl[buf][row * 64 + ((lg) ^ x) * 8];
            half8 k1 = *(const half8*)&Kl[buf][row * 64 + ((lg + 4) ^ x) * 8];
            sacc[tt] = MFMA16F(qf0, k0, sacc[tt], 0, 0, 0);
            sacc[tt] = MFMA16F(qf1, k1, sacc[tt], 0, 0, 0);
        }

        #pragma unroll
        for (int tt = 0; tt < 4; ++tt) {
            #pragma unroll
            for (int r = 0; r < 4; ++r) {
                float p = (mv[tt * 4 + r] != 0) ? __expf(sacc[tt][r] * 0.125f) : 0.0f;
                if      (r == 0) rs0 += p;
                else if (r == 1) rs1 += p;
                else if (r == 2) rs2 += p;
                else             rs3 += p;
                Pl[lg * 4 + r][tt * 16 + lr] = f2h(p);
            }
        }

        const half8 p0 = *(const half8*)&Pl[lr][lg * 8];
        const half8 p1 = *(const half8*)&Pl[lr][32 + lg * 8];
        #pragma unroll
        for (int vt = 0; vt < 4; ++vt) {
            int row = vt * 16 + lr, x = row & 7;
            half8 v0 = *(const half8*)&Vl[buf][row * 64 + ((lg) ^ x) * 8];
            half8 v1 = *(const half8*)&Vl[buf][row * 64 + ((lg + 4) ^ x) * 8];
            oacc[vt] = MFMA16F(p0, v0, oacc[vt], 0, 0, 0);
            oacc[vt] = MFMA16F(p1, v1, oacc[vt], 0, 0, 0);
        }
    }

    float rs[4] = {rs0, rs1, rs2, rs3};
    #pragma unroll
    for (int r = 0; r < 4; ++r) {
        float v = rs[r];
        v += __shfl_xor(v, 1, 64);
        v += __shfl_xor(v, 2, 64);
        v += __shfl_xor(v, 4, 64);
        v += __shfl_xor(v, 8, 64);
        rs[r] = 1.0f / v;
    }
    #pragma unroll
    for (int vt = 0; vt < 4; ++vt)
        #pragma unroll
        for (int r = 0; r < 4; ++r)
            out[((i64)b * SEQ + q0 + lg * 4 + r) * DH + vt * 16 + lr] = oacc[vt][r] * rs[r];
}

extern "C" void kernel_launch(void* const* d_in, const int* in_sizes, int n_in,
                              void* d_out, int out_size, void* d_ws, size_t ws_size,
                              hipStream_t stream) {
    const float* kh   = (const float*)d_in[0];
    const float* qh   = (const float*)d_in[1];
    const float* vh   = (const float*)d_in[2];
    const int*   mask = (const int*)  d_in[3];
    const float* Wq   = (const float*)d_in[4];
    const float* bq   = (const float*)d_in[5];
    const float* Wk   = (const float*)d_in[6];
    const float* bk   = (const float*)d_in[7];
    const float* Wv   = (const float*)d_in[8];
    const float* bv   = (const float*)d_in[9];
    float* out = (float*)d_out;

    u16* Wimg = (u16*)d_ws;                      // 3*16*4096 u16 = 384 KB
    u16* Qb   = Wimg + 3 * 16 * 4096;            // 2 MB each
    u16* Kb   = Qb + (i64)NB * SEQ * DH;
    u16* Vt   = Kb + (i64)NB * SEQ * DH;         // [b][vd][key]

    wimg_prep16<<<96, 256, 0, stream>>>(Wq, Wk, Wv, Wimg);
    proj_mfma12<<<dim3(512, 3), 256, 0, stream>>>(qh, kh, vh, Wimg,
                                                  bq, bk, bv, Qb, Kb, Vt);
    attn_mfma<<<1024, 64, 0, stream>>>(Qb, Kb, Vt, mask, out);
}

// Round 18
// 112.480 us; speedup vs baseline: 1.1248x; 1.0358x over previous
//
#include <hip/hip_runtime.h>

#define HIDDEN 1024
#define NB 8
#define SEQ 2048
#define DH 64

typedef long long i64;
typedef unsigned short u16;
typedef __attribute__((ext_vector_type(8))) _Float16 half8;  // 4 VGPRs = 8 fp16
typedef __attribute__((ext_vector_type(4))) float f32x4;

#define MFMA16F __builtin_amdgcn_mfma_f32_16x16x32_f16

__device__ __forceinline__ u16 f2h(float x) {
    _Float16 h = (_Float16)x;                 // RNE
    return __builtin_bit_cast(u16, h);
}
__device__ __forceinline__ void gl_lds16(const void* g, void* l) {
    __builtin_amdgcn_global_load_lds(
        (const __attribute__((address_space(1))) unsigned int*)g,
        (__attribute__((address_space(3))) unsigned int*)l, 16, 0, 0);
}

// ---------------------------------------------------------------------------
// Prepass: W[1024][64] (x3) -> Wimg[te][p][n][pos] fp16, p = 16 phases of
// BK=64, n = out col, pos = 16B block (8 per row); position pos holds global
// k-chunk (pos ^ (n&7)). (byte-identical to round-17 passing version)
// ---------------------------------------------------------------------------
__global__ __launch_bounds__(256) void wimg_prep16(
    const float* __restrict__ Wq, const float* __restrict__ Wk, const float* __restrict__ Wv,
    u16* __restrict__ Wimg)
{
    const int t = blockIdx.x * 256 + threadIdx.x;   // 24576 threads
    const int te = t >> 13;
    const int rem = t & 8191;
    const int p = rem >> 9;                          // 0..15
    const int rem2 = rem & 511;
    const int n = rem2 >> 3;                         // 0..63
    const int pos = rem2 & 7;                        // 16B block in row
    const float* W = te == 0 ? Wq : te == 1 ? Wk : Wv;
    const int g = pos ^ (n & 7);
    const int k0 = p * 64 + g * 8;
    u16* dst = Wimg + (i64)t * 8;
    #pragma unroll
    for (int j = 0; j < 8; ++j)
        dst[j] = f2h(W[(i64)(k0 + j) * DH + n]);
}

// ---------------------------------------------------------------------------
// Projection v13 = v8 skeleton x v12 bodies, BYTE-MINIMIZED:
// tile 64 rows x 64 cols (doubles rows/block vs v12) -> 768 blocks, W image
// staged 98 MB total (vs 196), A 192 MB; ~290 MB total staged.
// BK=64, 16 phases; per phase 24KB staged (16KB A + 8KB W). LDS 48KB
// -> EXACTLY 3 blocks/CU, all 768 blocks resident, no tail.
// Per phase: vmcnt(0) -> barrier -> stage(p+1) [6 gl_lds/wave] -> compute(p)
// [2 ks x (2 ds_read_b128 A + cvt + 4 MFMA)]. Wave w owns rows 16w..16w+15,
// all 64 cols. All index math verbatim from v12 (passing, 4.88e-4).
// ---------------------------------------------------------------------------
__global__ __launch_bounds__(256) void proj_mfma13(
    const float* __restrict__ qh, const float* __restrict__ kh, const float* __restrict__ vh,
    const u16* __restrict__ Wimg,
    const float* __restrict__ bq, const float* __restrict__ bk, const float* __restrict__ bv,
    u16* __restrict__ Qb, u16* __restrict__ Kb, u16* __restrict__ Vt)
{
    const int te = blockIdx.y;
    const float* A    = te == 0 ? qh : te == 1 ? kh : vh;
    const float* bias = te == 0 ? bq : te == 1 ? bk : bv;
    const int row0 = blockIdx.x << 6;          // 256 tiles of 64 rows
    const int t = threadIdx.x;
    const int w = t >> 6, lane = t & 63;
    const int lr = lane & 15, lg = lane >> 4;
    const int wr = w << 4;                     // wave row offset: 0,16,32,48

    __shared__ __attribute__((aligned(16))) float AL[2][64 * 64];   // 16KB x2
    __shared__ __attribute__((aligned(16))) u16  WL[2][64 * 64];    // 8KB x2

    const u16* Wte = Wimg + (i64)te * 16 * 4096;

    // A staging: wave w covers slab rows 16w..16w+15; gl_lds i covers 4 rows
    // (256B each, linear dst). Lane dst block = lane&15 of row
    // ar = 16w+4i+(lane>>4); SOURCE block = (lane&15) ^ (ar&15)   [rule 21]
    const float* asrc[4]; int adst[4];
    #pragma unroll
    for (int i = 0; i < 4; ++i) {
        const int ar = wr + 4 * i + (lane >> 4);             // slab row
        const int ab = (lane & 15) ^ (ar & 15);              // source 16B block
        asrc[i] = A + (i64)(row0 + ar) * HIDDEN + (ab << 2);
        adst[i] = (wr + 4 * i) * 64;
    }
    // W staging: wave w covers image rows 16w..16w+15; gl_lds j covers 8 rows
    const u16* wsrc[2]; int wdst[2];
    #pragma unroll
    for (int j = 0; j < 2; ++j) {
        const int n0 = wr + 8 * j;
        wsrc[j] = Wte + n0 * 64 + (lane << 3);               // linear image
        wdst[j] = n0 * 64;
    }

    f32x4 acc[4] = {};

#define STAGE(P, B) { \
        _Pragma("unroll") \
        for (int i_ = 0; i_ < 4; ++i_) \
            gl_lds16(asrc[i_] + (P) * 64, &AL[B][adst[i_]]); \
        _Pragma("unroll") \
        for (int j_ = 0; j_ < 2; ++j_) \
            gl_lds16(wsrc[j_] + (P) * 4096, &WL[B][wdst[j_]]); }

#define COMPUTE(B) { \
        _Pragma("unroll") \
        for (int ks = 0; ks < 2; ++ks) { \
            const int b0 = ks * 8 + lg * 2; \
            const float4 fa = *(const float4*)&AL[B][(wr + lr) * 64 + ((b0 ^ lr) << 2)]; \
            const float4 fb = *(const float4*)&AL[B][(wr + lr) * 64 + (((b0 + 1) ^ lr) << 2)]; \
            half8 a; \
            a[0] = (_Float16)fa.x; a[1] = (_Float16)fa.y; \
            a[2] = (_Float16)fa.z; a[3] = (_Float16)fa.w; \
            a[4] = (_Float16)fb.x; a[5] = (_Float16)fb.y; \
            a[6] = (_Float16)fb.z; a[7] = (_Float16)fb.w; \
            _Pragma("unroll") \
            for (int nt = 0; nt < 4; ++nt) { \
                const int n = nt * 16 + lr; \
                const int pos = (ks * 4 + lg) ^ (n & 7); \
                const half8 b = *(const half8*)&WL[B][n * 64 + (pos << 3)]; \
                acc[nt] = MFMA16F(a, b, acc[nt], 0, 0, 0); \
            } \
        } }

    STAGE(0, 0)

    int buf = 0;
    #pragma unroll 1
    for (int p = 0; p < 16; ++p) {
        asm volatile("s_waitcnt vmcnt(0)" ::: "memory");   // stage(p) done
        __syncthreads();                                    // visible; buf^1 free
        if (p < 15) STAGE(p + 1, buf ^ 1)
        COMPUTE(buf)
        buf ^= 1;
    }
#undef STAGE
#undef COMPUTE

    // epilogue: D layout col=lane&15 (within nt), row=(lane>>4)*4+reg
    #pragma unroll
    for (int nt = 0; nt < 4; ++nt) {
        const int col = nt * 16 + lr;
        const float bb = bias[col];
        #pragma unroll
        for (int r = 0; r < 4; ++r) {
            const i64 grow = row0 + wr + (lg << 2) + r;
            const u16 v = f2h(acc[nt][r] + bb);
            if (te == 0)      Qb[grow * DH + col] = v;
            else if (te == 1) Kb[grow * DH + col] = v;
            else {
                const i64 bb2 = grow >> 11, key = grow & 2047;
                Vt[(bb2 * DH + col) * SEQ + key] = v;
            }
        }
    }
}

// ---------------------------------------------------------------------------
// Attention: 1024 single-wave blocks (16 q-rows each), no barriers.
// (byte-identical to the round-17 passing fp16 version)
// ---------------------------------------------------------------------------
__global__ __launch_bounds__(64) void attn_mfma(
    const u16* __restrict__ Qb, const u16* __restrict__ Kb, const u16* __restrict__ Vt,
    const int* __restrict__ mask, float* __restrict__ out)
{
    __shared__ __attribute__((aligned(16))) u16 Kl[2][64 * 64];
    __shared__ __attribute__((aligned(16))) u16 Vl[2][64 * 64];
    __shared__ __attribute__((aligned(16))) u16 Pl[16][72];

    const int lane = threadIdx.x;
    const int lr = lane & 15, lg = lane >> 4;
    const int b  = blockIdx.x >> 7;
    const int q0 = (blockIdx.x & 127) << 4;

    const i64 qrow = (i64)b * SEQ + q0 + lr;
    const half8 qf0 = *(const half8*)(Qb + qrow * DH + lg * 8);
    const half8 qf1 = *(const half8*)(Qb + qrow * DH + 32 + lg * 8);

    const int srow = lane >> 3;   // 0..7 (+8i)
    const int scb  = lane & 7;    // 16B block

    f32x4 oacc[4] = {};
    float rs0 = 0.f, rs1 = 0.f, rs2 = 0.f, rs3 = 0.f;

    // prologue: stage tile 0 into buf 0 (16 loads)
    {
        const i64 kbase = (i64)b * SEQ;
        #pragma unroll
        for (int i = 0; i < 8; ++i) {
            int row = i * 8 + srow, cb = scb ^ (row & 7);
            gl_lds16(Kb + (kbase + row) * DH + cb * 8, &Kl[0][i * 512]);
        }
        #pragma unroll
        for (int i = 0; i < 8; ++i) {
            int row = i * 8 + srow, cb = scb ^ (row & 7);
            gl_lds16(Vt + ((i64)b * DH + row) * SEQ + cb * 8, &Vl[0][i * 512]);
        }
    }

    #pragma unroll 1
    for (int t = 0; t < 32; ++t) {
        const int kt = t * 64;
        const int buf = t & 1;

        int mv[16];
        #pragma unroll
        for (int tt = 0; tt < 4; ++tt)
            #pragma unroll
            for (int r = 0; r < 4; ++r)
                mv[tt * 4 + r] =
                    mask[((i64)b * SEQ + q0 + lg * 4 + r) * SEQ + kt + tt * 16 + lr];

        if (t < 31) {
            const int kn = kt + 64;
            const i64 kbase = (i64)b * SEQ + kn;
            #pragma unroll
            for (int i = 0; i < 8; ++i) {
                int row = i * 8 + srow, cb = scb ^ (row & 7);
                gl_lds16(Kb + (kbase + row) * DH + cb * 8, &Kl[buf ^ 1][i * 512]);
            }
            #pragma unroll
            for (int i = 0; i < 8; ++i) {
                int row = i * 8 + srow, cb = scb ^ (row & 7);
                gl_lds16(Vt + ((i64)b * DH + row) * SEQ + kn + cb * 8, &Vl[buf ^ 1][i * 512]);
            }
            asm volatile("s_waitcnt vmcnt(32)" ::: "memory");
        } else {
            asm volatile("s_waitcnt vmcnt(16)" ::: "memory");
        }

        f32x4 sacc[4] = {};
        #pragma unroll
        for (int tt = 0; tt < 4; ++tt) {
            int row = tt * 16 + lr, x = row & 7;
            half8 k0 = *(const half8*)&Kl[buf][row * 64 + ((lg) ^ x) * 8];
            half8 k1 = *(const half8*)&Kl[buf][row * 64 + ((lg + 4) ^ x) * 8];
            sacc[tt] = MFMA16F(qf0, k0, sacc[tt], 0, 0, 0);
            sacc[tt] = MFMA16F(qf1, k1, sacc[tt], 0, 0, 0);
        }

        #pragma unroll
        for (int tt = 0; tt < 4; ++tt) {
            #pragma unroll
            for (int r = 0; r < 4; ++r) {
                float p = (mv[tt * 4 + r] != 0) ? __expf(sacc[tt][r] * 0.125f) : 0.0f;
                if      (r == 0) rs0 += p;
                else if (r == 1) rs1 += p;
                else if (r == 2) rs2 += p;
                else             rs3 += p;
                Pl[lg * 4 + r][tt * 16 + lr] = f2h(p);
            }
        }

        const half8 p0 = *(const half8*)&Pl[lr][lg * 8];
        const half8 p1 = *(const half8*)&Pl[lr][32 + lg * 8];
        #pragma unroll
        for (int vt = 0; vt < 4; ++vt) {
            int row = vt * 16 + lr, x = row & 7;
            half8 v0 = *(const half8*)&Vl[buf][row * 64 + ((lg) ^ x) * 8];
            half8 v1 = *(const half8*)&Vl[buf][row * 64 + ((lg + 4) ^ x) * 8];
            oacc[vt] = MFMA16F(p0, v0, oacc[vt], 0, 0, 0);
            oacc[vt] = MFMA16F(p1, v1, oacc[vt], 0, 0, 0);
        }
    }

    float rs[4] = {rs0, rs1, rs2, rs3};
    #pragma unroll
    for (int r = 0; r < 4; ++r) {
        float v = rs[r];
        v += __shfl_xor(v, 1, 64);
        v += __shfl_xor(v, 2, 64);
        v += __shfl_xor(v, 4, 64);
        v += __shfl_xor(v, 8, 64);
        rs[r] = 1.0f / v;
    }
    #pragma unroll
    for (int vt = 0; vt < 4; ++vt)
        #pragma unroll
        for (int r = 0; r < 4; ++r)
            out[((i64)b * SEQ + q0 + lg * 4 + r) * DH + vt * 16 + lr] = oacc[vt][r] * rs[r];
}

extern "C" void kernel_launch(void* const* d_in, const int* in_sizes, int n_in,
                              void* d_out, int out_size, void* d_ws, size_t ws_size,
                              hipStream_t stream) {
    const float* kh   = (const float*)d_in[0];
    const float* qh   = (const float*)d_in[1];
    const float* vh   = (const float*)d_in[2];
    const int*   mask = (const int*)  d_in[3];
    const float* Wq   = (const float*)d_in[4];
    const float* bq   = (const float*)d_in[5];
    const float* Wk   = (const float*)d_in[6];
    const float* bk   = (const float*)d_in[7];
    const float* Wv   = (const float*)d_in[8];
    const float* bv   = (const float*)d_in[9];
    float* out = (float*)d_out;

    u16* Wimg = (u16*)d_ws;                      // 3*16*4096 u16 = 384 KB
    u16* Qb   = Wimg + 3 * 16 * 4096;            // 2 MB each
    u16* Kb   = Qb + (i64)NB * SEQ * DH;
    u16* Vt   = Kb + (i64)NB * SEQ * DH;         // [b][vd][key]

    wimg_prep16<<<96, 256, 0, stream>>>(Wq, Wk, Wv, Wimg);
    proj_mfma13<<<dim3(256, 3), 256, 0, stream>>>(qh, kh, vh, Wimg,
                                                  bq, bk, bv, Qb, Kb, Vt);
    attn_mfma<<<1024, 64, 0, stream>>>(Qb, Kb, Vt, mask, out);
}

// Round 19
// 108.386 us; speedup vs baseline: 1.1673x; 1.0378x over previous
//
#include <hip/hip_runtime.h>

#define HIDDEN 1024
#define NB 8
#define SEQ 2048
#define DH 64

typedef long long i64;
typedef unsigned short u16;
typedef __attribute__((ext_vector_type(8))) _Float16 half8;  // 4 VGPRs = 8 fp16
typedef __attribute__((ext_vector_type(4))) float f32x4;

#define MFMA16F __builtin_amdgcn_mfma_f32_16x16x32_f16

__device__ __forceinline__ u16 f2h(float x) {
    _Float16 h = (_Float16)x;                 // RNE
    return __builtin_bit_cast(u16, h);
}
__device__ __forceinline__ void gl_lds16(const void* g, void* l) {
    __builtin_amdgcn_global_load_lds(
        (const __attribute__((address_space(1))) unsigned int*)g,
        (__attribute__((address_space(3))) unsigned int*)l, 16, 0, 0);
}

// ---------------------------------------------------------------------------
// Prepass: W[1024][64] (x3) -> Wimg[te][p][n][pos] fp16, p = 16 phases of
// BK=64, n = out col, pos = 16B block (8 per row); position pos holds global
// k-chunk (pos ^ (n&7)). (byte-identical to round-18 passing version)
// ---------------------------------------------------------------------------
__global__ __launch_bounds__(256) void wimg_prep16(
    const float* __restrict__ Wq, const float* __restrict__ Wk, const float* __restrict__ Wv,
    u16* __restrict__ Wimg)
{
    const int t = blockIdx.x * 256 + threadIdx.x;   // 24576 threads
    const int te = t >> 13;
    const int rem = t & 8191;
    const int p = rem >> 9;                          // 0..15
    const int rem2 = rem & 511;
    const int n = rem2 >> 3;                         // 0..63
    const int pos = rem2 & 7;                        // 16B block in row
    const float* W = te == 0 ? Wq : te == 1 ? Wk : Wv;
    const int g = pos ^ (n & 7);
    const int k0 = p * 64 + g * 8;
    u16* dst = Wimg + (i64)t * 8;
    #pragma unroll
    for (int j = 0; j < 8; ++j)
        dst[j] = f2h(W[(i64)(k0 + j) * DH + n]);
}

// ---------------------------------------------------------------------------
// Projection v13 (unchanged, session best): v8 skeleton x v12 bodies,
// 64x64 tile, BK=64, 16 phases, LDS 48KB -> 3 blocks/CU, all resident.
// A-from-L3 ~3 TB/s is this op's measured platform floor (13 variants).
// ---------------------------------------------------------------------------
__global__ __launch_bounds__(256) void proj_mfma13(
    const float* __restrict__ qh, const float* __restrict__ kh, const float* __restrict__ vh,
    const u16* __restrict__ Wimg,
    const float* __restrict__ bq, const float* __restrict__ bk, const float* __restrict__ bv,
    u16* __restrict__ Qb, u16* __restrict__ Kb, u16* __restrict__ Vt)
{
    const int te = blockIdx.y;
    const float* A    = te == 0 ? qh : te == 1 ? kh : vh;
    const float* bias = te == 0 ? bq : te == 1 ? bk : bv;
    const int row0 = blockIdx.x << 6;          // 256 tiles of 64 rows
    const int t = threadIdx.x;
    const int w = t >> 6, lane = t & 63;
    const int lr = lane & 15, lg = lane >> 4;
    const int wr = w << 4;                     // wave row offset: 0,16,32,48

    __shared__ __attribute__((aligned(16))) float AL[2][64 * 64];   // 16KB x2
    __shared__ __attribute__((aligned(16))) u16  WL[2][64 * 64];    // 8KB x2

    const u16* Wte = Wimg + (i64)te * 16 * 4096;

    const float* asrc[4]; int adst[4];
    #pragma unroll
    for (int i = 0; i < 4; ++i) {
        const int ar = wr + 4 * i + (lane >> 4);             // slab row
        const int ab = (lane & 15) ^ (ar & 15);              // source 16B block
        asrc[i] = A + (i64)(row0 + ar) * HIDDEN + (ab << 2);
        adst[i] = (wr + 4 * i) * 64;
    }
    const u16* wsrc[2]; int wdst[2];
    #pragma unroll
    for (int j = 0; j < 2; ++j) {
        const int n0 = wr + 8 * j;
        wsrc[j] = Wte + n0 * 64 + (lane << 3);               // linear image
        wdst[j] = n0 * 64;
    }

    f32x4 acc[4] = {};

#define STAGE(P, B) { \
        _Pragma("unroll") \
        for (int i_ = 0; i_ < 4; ++i_) \
            gl_lds16(asrc[i_] + (P) * 64, &AL[B][adst[i_]]); \
        _Pragma("unroll") \
        for (int j_ = 0; j_ < 2; ++j_) \
            gl_lds16(wsrc[j_] + (P) * 4096, &WL[B][wdst[j_]]); }

#define COMPUTE(B) { \
        _Pragma("unroll") \
        for (int ks = 0; ks < 2; ++ks) { \
            const int b0 = ks * 8 + lg * 2; \
            const float4 fa = *(const float4*)&AL[B][(wr + lr) * 64 + ((b0 ^ lr) << 2)]; \
            const float4 fb = *(const float4*)&AL[B][(wr + lr) * 64 + (((b0 + 1) ^ lr) << 2)]; \
            half8 a; \
            a[0] = (_Float16)fa.x; a[1] = (_Float16)fa.y; \
            a[2] = (_Float16)fa.z; a[3] = (_Float16)fa.w; \
            a[4] = (_Float16)fb.x; a[5] = (_Float16)fb.y; \
            a[6] = (_Float16)fb.z; a[7] = (_Float16)fb.w; \
            _Pragma("unroll") \
            for (int nt = 0; nt < 4; ++nt) { \
                const int n = nt * 16 + lr; \
                const int pos = (ks * 4 + lg) ^ (n & 7); \
                const half8 b = *(const half8*)&WL[B][n * 64 + (pos << 3)]; \
                acc[nt] = MFMA16F(a, b, acc[nt], 0, 0, 0); \
            } \
        } }

    STAGE(0, 0)

    int buf = 0;
    #pragma unroll 1
    for (int p = 0; p < 16; ++p) {
        asm volatile("s_waitcnt vmcnt(0)" ::: "memory");   // stage(p) done
        __syncthreads();                                    // visible; buf^1 free
        if (p < 15) STAGE(p + 1, buf ^ 1)
        COMPUTE(buf)
        buf ^= 1;
    }
#undef STAGE
#undef COMPUTE

    #pragma unroll
    for (int nt = 0; nt < 4; ++nt) {
        const int col = nt * 16 + lr;
        const float bb = bias[col];
        #pragma unroll
        for (int r = 0; r < 4; ++r) {
            const i64 grow = row0 + wr + (lg << 2) + r;
            const u16 v = f2h(acc[nt][r] + bb);
            if (te == 0)      Qb[grow * DH + col] = v;
            else if (te == 1) Kb[grow * DH + col] = v;
            else {
                const i64 bb2 = grow >> 11, key = grow & 2047;
                Vt[(bb2 * DH + col) * SEQ + key] = v;
            }
        }
    }
}

// ---------------------------------------------------------------------------
// Attention v2 = round-18 passing kernel + XCD-aware block swizzle (T1).
// Bijective remap id2 = (bid&7)*128 + (bid>>3): with round-robin block->XCD
// dispatch, XCD c receives exactly batch c's 128 q-tile blocks, so each
// XCD's L2 holds only its own batch's K/V (512 KB vs 4 MB) -> the 536 MB
// of K/V staging becomes solidly L2-hit. Work is bit-identical.
// ---------------------------------------------------------------------------
__global__ __launch_bounds__(64) void attn_mfma(
    const u16* __restrict__ Qb, const u16* __restrict__ Kb, const u16* __restrict__ Vt,
    const int* __restrict__ mask, float* __restrict__ out)
{
    __shared__ __attribute__((aligned(16))) u16 Kl[2][64 * 64];
    __shared__ __attribute__((aligned(16))) u16 Vl[2][64 * 64];
    __shared__ __attribute__((aligned(16))) u16 Pl[16][72];

    const int lane = threadIdx.x;
    const int lr = lane & 15, lg = lane >> 4;
    const int bid = blockIdx.x;
    const int id2 = (bid & 7) * 128 + (bid >> 3);   // bijective XCD swizzle
    const int b  = id2 >> 7;
    const int q0 = (id2 & 127) << 4;

    const i64 qrow = (i64)b * SEQ + q0 + lr;
    const half8 qf0 = *(const half8*)(Qb + qrow * DH + lg * 8);
    const half8 qf1 = *(const half8*)(Qb + qrow * DH + 32 + lg * 8);

    const int srow = lane >> 3;   // 0..7 (+8i)
    const int scb  = lane & 7;    // 16B block

    f32x4 oacc[4] = {};
    float rs0 = 0.f, rs1 = 0.f, rs2 = 0.f, rs3 = 0.f;

    // prologue: stage tile 0 into buf 0 (16 loads)
    {
        const i64 kbase = (i64)b * SEQ;
        #pragma unroll
        for (int i = 0; i < 8; ++i) {
            int row = i * 8 + srow, cb = scb ^ (row & 7);
            gl_lds16(Kb + (kbase + row) * DH + cb * 8, &Kl[0][i * 512]);
        }
        #pragma unroll
        for (int i = 0; i < 8; ++i) {
            int row = i * 8 + srow, cb = scb ^ (row & 7);
            gl_lds16(Vt + ((i64)b * DH + row) * SEQ + cb * 8, &Vl[0][i * 512]);
        }
    }

    #pragma unroll 1
    for (int t = 0; t < 32; ++t) {
        const int kt = t * 64;
        const int buf = t & 1;

        int mv[16];
        #pragma unroll
        for (int tt = 0; tt < 4; ++tt)
            #pragma unroll
            for (int r = 0; r < 4; ++r)
                mv[tt * 4 + r] =
                    mask[((i64)b * SEQ + q0 + lg * 4 + r) * SEQ + kt + tt * 16 + lr];

        if (t < 31) {
            const int kn = kt + 64;
            const i64 kbase = (i64)b * SEQ + kn;
            #pragma unroll
            for (int i = 0; i < 8; ++i) {
                int row = i * 8 + srow, cb = scb ^ (row & 7);
                gl_lds16(Kb + (kbase + row) * DH + cb * 8, &Kl[buf ^ 1][i * 512]);
            }
            #pragma unroll
            for (int i = 0; i < 8; ++i) {
                int row = i * 8 + srow, cb = scb ^ (row & 7);
                gl_lds16(Vt + ((i64)b * DH + row) * SEQ + kn + cb * 8, &Vl[buf ^ 1][i * 512]);
            }
            asm volatile("s_waitcnt vmcnt(32)" ::: "memory");
        } else {
            asm volatile("s_waitcnt vmcnt(16)" ::: "memory");
        }

        f32x4 sacc[4] = {};
        #pragma unroll
        for (int tt = 0; tt < 4; ++tt) {
            int row = tt * 16 + lr, x = row & 7;
            half8 k0 = *(const half8*)&Kl[buf][row * 64 + ((lg) ^ x) * 8];
            half8 k1 = *(const half8*)&Kl[buf][row * 64 + ((lg + 4) ^ x) * 8];
            sacc[tt] = MFMA16F(qf0, k0, sacc[tt], 0, 0, 0);
            sacc[tt] = MFMA16F(qf1, k1, sacc[tt], 0, 0, 0);
        }

        #pragma unroll
        for (int tt = 0; tt < 4; ++tt) {
            #pragma unroll
            for (int r = 0; r < 4; ++r) {
                float p = (mv[tt * 4 + r] != 0) ? __expf(sacc[tt][r] * 0.125f) : 0.0f;
                if      (r == 0) rs0 += p;
                else if (r == 1) rs1 += p;
                else if (r == 2) rs2 += p;
                else             rs3 += p;
                Pl[lg * 4 + r][tt * 16 + lr] = f2h(p);
            }
        }

        const half8 p0 = *(const half8*)&Pl[lr][lg * 8];
        const half8 p1 = *(const half8*)&Pl[lr][32 + lg * 8];
        #pragma unroll
        for (int vt = 0; vt < 4; ++vt) {
            int row = vt * 16 + lr, x = row & 7;
            half8 v0 = *(const half8*)&Vl[buf][row * 64 + ((lg) ^ x) * 8];
            half8 v1 = *(const half8*)&Vl[buf][row * 64 + ((lg + 4) ^ x) * 8];
            oacc[vt] = MFMA16F(p0, v0, oacc[vt], 0, 0, 0);
            oacc[vt] = MFMA16F(p1, v1, oacc[vt], 0, 0, 0);
        }
    }

    float rs[4] = {rs0, rs1, rs2, rs3};
    #pragma unroll
    for (int r = 0; r < 4; ++r) {
        float v = rs[r];
        v += __shfl_xor(v, 1, 64);
        v += __shfl_xor(v, 2, 64);
        v += __shfl_xor(v, 4, 64);
        v += __shfl_xor(v, 8, 64);
        rs[r] = 1.0f / v;
    }
    #pragma unroll
    for (int vt = 0; vt < 4; ++vt)
        #pragma unroll
        for (int r = 0; r < 4; ++r)
            out[((i64)b * SEQ + q0 + lg * 4 + r) * DH + vt * 16 + lr] = oacc[vt][r] * rs[r];
}

extern "C" void kernel_launch(void* const* d_in, const int* in_sizes, int n_in,
                              void* d_out, int out_size, void* d_ws, size_t ws_size,
                              hipStream_t stream) {
    const float* kh   = (const float*)d_in[0];
    const float* qh   = (const float*)d_in[1];
    const float* vh   = (const float*)d_in[2];
    const int*   mask = (const int*)  d_in[3];
    const float* Wq   = (const float*)d_in[4];
    const float* bq   = (const float*)d_in[5];
    const float* Wk   = (const float*)d_in[6];
    const float* bk   = (const float*)d_in[7];
    const float* Wv   = (const float*)d_in[8];
    const float* bv   = (const float*)d_in[9];
    float* out = (float*)d_out;

    u16* Wimg = (u16*)d_ws;                      // 3*16*4096 u16 = 384 KB
    u16* Qb   = Wimg + 3 * 16 * 4096;            // 2 MB each
    u16* Kb   = Qb + (i64)NB * SEQ * DH;
    u16* Vt   = Kb + (i64)NB * SEQ * DH;         // [b][vd][key]

    wimg_prep16<<<96, 256, 0, stream>>>(Wq, Wk, Wv, Wimg);
    proj_mfma13<<<dim3(256, 3), 256, 0, stream>>>(qh, kh, vh, Wimg,
                                                  bq, bk, bv, Qb, Kb, Vt);
    attn_mfma<<<1024, 64, 0, stream>>>(Qb, Kb, Vt, mask, out);
}